// Round 10
// baseline (295.036 us; speedup 1.0000x reference)
//
#include <hip/hip_runtime.h>
#include <hip/hip_bf16.h>

#define K_DIM 256
#define RSTRIDE 128   // padded CSR row stride; in-deg max ~58 (Binomial mean 32), 2x margin
#define EPB 8192      // edges per split chunk (sorted buffer = 32 KB LDS)

// bucket geometry (bucket = 32 dst rows for CSR build; src buckets for out-degree)
#define G0_DB 625     // graph0 dst buckets (625*32 = 20000)
#define G0_SB 256     // graph0 src buckets
#define G0_SW 392     // nodes per src bucket (256*392 >= 100000)
#define G1_DB 128     // graph1 dst buckets (128*32 = 4096)
#define G1_SB 64
#define G1_SW 313     // 64*313 >= 20000

#define NB_FIN (G0_DB + G1_DB + G0_SB + G1_SB)   // 1073 finalize jobs
#define CAST_BLKS 2048                            // grid-stride cast blocks in castfin

typedef short bf16x8 __attribute__((ext_vector_type(8)));
typedef float f32x4 __attribute__((ext_vector_type(4)));

static __device__ __forceinline__ unsigned short f2bf(float x) {
    __hip_bfloat16 b = __float2bfloat16(x);   // RNE
    return *reinterpret_cast<unsigned short*>(&b);
}
static __device__ __forceinline__ float bflo(unsigned int p) {
    return __uint_as_float(p << 16);
}
static __device__ __forceinline__ float bfhi(unsigned int p) {
    return __uint_as_float(p & 0xffff0000u);
}

// ---- block-wide exclusive scan of hist[0..M) -> offs[0..M) (tmp[256]) ----
static __device__ __forceinline__ void block_exscan(
        const int* __restrict__ hist, int* __restrict__ offs, int* __restrict__ tmp, int M) {
    const int tid = threadIdx.x;
    const int S = (M + 255) >> 8;        // strip length per thread
    const int base = tid * S;
    int sum = 0;
    for (int k = 0; k < S; ++k) {
        int idx = base + k;
        if (idx < M) sum += hist[idx];
    }
    tmp[tid] = sum;
    __syncthreads();
    // Hillis-Steele inclusive scan over 256 strip sums
    for (int d = 1; d < 256; d <<= 1) {
        int v = tmp[tid];
        int u = (tid >= d) ? tmp[tid - d] : 0;
        __syncthreads();
        tmp[tid] = v + u;
        __syncthreads();
    }
    int run = (tid == 0) ? 0 : tmp[tid - 1];
    for (int k = 0; k < S; ++k) {
        int idx = base + k;
        if (idx < M) { offs[idx] = run; run += hist[idx]; }
    }
    __syncthreads();
}

struct SplitSh {
    int hist[640];
    int offs[640];
    int tmp[256];
    unsigned sorted[EPB];
};  // 38.9 KB; only 95+48 blocks exist, all co-resident -> size irrelevant

// ---- per-chunk LDS counting sort, BOTH keys, all-coalesced global writes ----
template <int NDB, int NSB, int SW>
static __device__ __forceinline__ void split_sort(
        const int* __restrict__ src, const int* __restrict__ dst, int E, int chunk,
        int* __restrict__ cntD, int* __restrict__ offD,
        int* __restrict__ cntS, int* __restrict__ offS,
        unsigned* __restrict__ sortD, unsigned* __restrict__ sortS, SplitSh& sh) {
    const int tid = threadIdx.x;
    const int e0 = chunk * EPB;
    const int n = min(EPB, E - e0);
    // ---------- dst key ----------
    for (int i = tid; i < NDB; i += 256) sh.hist[i] = 0;
    __syncthreads();
    for (int j = tid; j < n; j += 256) atomicAdd(&sh.hist[dst[e0 + j] >> 5], 1);
    __syncthreads();
    block_exscan(sh.hist, sh.offs, sh.tmp, NDB);
    for (int i = tid; i < NDB; i += 256) {
        cntD[chunk * NDB + i] = sh.hist[i];
        offD[chunk * NDB + i] = sh.offs[i];
    }
    __syncthreads();
    for (int j = tid; j < n; j += 256) {
        int d = dst[e0 + j];
        int s = src[e0 + j];
        int pos = atomicAdd(&sh.offs[d >> 5], 1);        // LDS cursor; pos < n always
        sh.sorted[pos] = ((unsigned)s << 5) | (unsigned)(d & 31);
    }
    __syncthreads();
    {
        unsigned* __restrict__ gout = sortD + (size_t)chunk * EPB;
        for (int j = tid; j < n; j += 256) gout[j] = sh.sorted[j];   // coalesced
    }
    __syncthreads();
    // ---------- src key ----------
    for (int i = tid; i < NSB; i += 256) sh.hist[i] = 0;
    __syncthreads();
    for (int j = tid; j < n; j += 256)
        atomicAdd(&sh.hist[(int)((unsigned)src[e0 + j] / SW)], 1);
    __syncthreads();
    block_exscan(sh.hist, sh.offs, sh.tmp, NSB);
    for (int i = tid; i < NSB; i += 256) {
        cntS[chunk * NSB + i] = sh.hist[i];
        offS[chunk * NSB + i] = sh.offs[i];
    }
    __syncthreads();
    for (int j = tid; j < n; j += 256) {
        unsigned s = (unsigned)src[e0 + j];
        int pos = atomicAdd(&sh.offs[s / SW], 1);
        sh.sorted[pos] = s;
    }
    __syncthreads();
    {
        unsigned* __restrict__ gout = sortS + (size_t)chunk * EPB;
        for (int j = tid; j < n; j += 256) gout[j] = sh.sorted[j];   // coalesced
    }
}

// ---- splitA: edge sort (graph0+graph1) + weight packs ----
__global__ __launch_bounds__(256) void splitA_kernel(
        const int* __restrict__ src0, const int* __restrict__ dst0, int E0,
        const int* __restrict__ src1, const int* __restrict__ dst1, int E1,
        int* __restrict__ cntD0, int* __restrict__ offD0,
        int* __restrict__ cntS0, int* __restrict__ offS0,
        unsigned* __restrict__ sortD0, unsigned* __restrict__ sortS0,
        int* __restrict__ cntD1, int* __restrict__ offD1,
        int* __restrict__ cntS1, int* __restrict__ offS1,
        unsigned* __restrict__ sortD1, unsigned* __restrict__ sortS1,
        int nA0, int nA1,
        const float* __restrict__ W1, uint4* __restrict__ pw1,
        const float* __restrict__ W2, uint4* __restrict__ pw2) {
    __shared__ SplitSh sh;
    const int b = blockIdx.x;
    if (b < nA0) {
        split_sort<G0_DB, G0_SB, G0_SW>(src0, dst0, E0, b,
                                        cntD0, offD0, cntS0, offS0, sortD0, sortS0, sh);
    } else if (b < nA0 + nA1) {
        split_sort<G1_DB, G1_SB, G1_SW>(src1, dst1, E1, b - nA0,
                                        cntD1, offD1, cntS1, offS1, sortD1, sortS1, sh);
    } else if (b < nA0 + nA1 + 32) {
        // pack W1 (256x256 f32 [k][n]) -> bf16 B-frag layout:
        // pw[(nt*8+kt)*64+lane] = W[kt*32+(lane>>4)*8+j][nt*16+(lane&15)], j=0..7
        int idx = (b - nA0 - nA1) * blockDim.x + threadIdx.x;   // 0..8191
        int lane = idx & 63;
        int kt = (idx >> 6) & 7;
        int nt = idx >> 9;
        int n = nt * 16 + (lane & 15);
        int k = kt * 32 + (lane >> 4) * 8;
        union { unsigned short us[8]; uint4 u; } o;
#pragma unroll
        for (int j = 0; j < 8; ++j) o.us[j] = f2bf(W1[(size_t)(k + j) * 256 + n]);
        pw1[idx] = o.u;
    } else {
        int idx = (b - nA0 - nA1 - 32) * blockDim.x + threadIdx.x; // 0..4095
        int lane = idx & 63;
        int kt = (idx >> 6) & 7;
        int nt = idx >> 9;
        int n = nt * 16 + (lane & 15);
        int k = kt * 32 + (lane >> 4) * 8;
        union { unsigned short us[8]; uint4 u; } o;
#pragma unroll
        for (int j = 0; j < 8; ++j) o.us[j] = f2bf(W2[(size_t)(k + j) * 128 + n]);
        pw2[idx] = o.u;
    }
}

// ---- finalize dst-bucket: stage 32-row padded CSR tile in LDS, stream out ----
template <int NDB, int GT>
static __device__ __forceinline__ void fin_dst(
        const unsigned* __restrict__ sortD, const int* __restrict__ cntD,
        const int* __restrict__ offD, int nblk, int b,
        int* __restrict__ esrc, int* __restrict__ cnt, int* tile, int* rowc) {
    const int tid = threadIdx.x;
    if (tid < 32) rowc[tid] = 0;
    __syncthreads();
    for (int rr = tid / GT; rr < nblk; rr += 256 / GT) {
        const int c = cntD[rr * NDB + b];
        const int o = offD[rr * NDB + b];
        const unsigned* __restrict__ seg = sortD + (size_t)rr * EPB + o;  // contiguous run
        for (int j = tid % GT; j < c; j += GT) {
            unsigned v = seg[j];
            int dloc = v & 31;
            int s = (int)(v >> 5);
            int slot = atomicAdd(&rowc[dloc], 1);
            if (slot < RSTRIDE) tile[(dloc << 7) + slot] = s;
        }
    }
    __syncthreads();
    // coalesced 16 KB stream: tile layout == global padded-CSR layout
    int* __restrict__ gout = esrc + ((size_t)b << 12);
    for (int i = tid; i < 32 * RSTRIDE; i += 256) gout[i] = tile[i];
    if (tid < 32) cnt[b * 32 + tid] = rowc[tid];   // true (uncapped) in-degree
}

// ---- finalize src-bucket: out-degree histogram -> f32 norm table ----
template <int NSB, int SW, int GT>
static __device__ __forceinline__ void fin_src(
        const unsigned* __restrict__ sortS, const int* __restrict__ cntS,
        const int* __restrict__ offS, int nblk, int b, int NN,
        float* __restrict__ nv, int* hist) {
    const int tid = threadIdx.x;
    for (int i = tid; i < SW; i += 256) hist[i] = 0;
    __syncthreads();
    const int base = b * SW;
    for (int rr = tid / GT; rr < nblk; rr += 256 / GT) {
        const int c = cntS[rr * NSB + b];
        const int o = offS[rr * NSB + b];
        const unsigned* __restrict__ seg = sortS + (size_t)rr * EPB + o;
        for (int j = tid % GT; j < c; j += GT)
            atomicAdd(&hist[(int)seg[j] - base], 1);
    }
    __syncthreads();
    for (int i = tid; i < SW; i += 256) {
        int node = base + i;
        if (node < NN) nv[node] = rsqrtf((float)max(hist[i], 1));   // dense write
    }
}

// ---- castfin: grid-stride feature cast (blocks FIRST — it is the long pole)
// + finalize jobs. Cast: 64 B read / 32 B write per thread-iter. ----
__global__ __launch_bounds__(256) void castfin_kernel(
        int nA0, int nA1,
        const unsigned* __restrict__ sortD0, const int* __restrict__ cntD0,
        const int* __restrict__ offD0, int* __restrict__ cnt0, int* __restrict__ esrc0,
        const unsigned* __restrict__ sortD1, const int* __restrict__ cntD1,
        const int* __restrict__ offD1, int* __restrict__ cnt1, int* __restrict__ esrc1,
        const unsigned* __restrict__ sortS0, const int* __restrict__ cntS0,
        const int* __restrict__ offS0, float* __restrict__ nv0,
        const unsigned* __restrict__ sortS1, const int* __restrict__ cntS1,
        const int* __restrict__ offS1, float* __restrict__ nv1,
        const float* __restrict__ feat, unsigned short* __restrict__ h, int numVec16) {
    __shared__ union {
        struct { int tile[32 * RSTRIDE]; int rowc[32]; } d;   // 16.1 KB
        int hist[G0_SW];
    } sh;
    int b = blockIdx.x;
    if (b < CAST_BLKS) {
        // grid-stride cast: v-th 16-float vector -> 16 bf16
        for (int v = b * 256 + (int)threadIdx.x; v < numVec16; v += CAST_BLKS * 256) {
            const int idx = v * 16;
            const float4 v0 = *reinterpret_cast<const float4*>(feat + idx);
            const float4 v1 = *reinterpret_cast<const float4*>(feat + idx + 4);
            const float4 v2 = *reinterpret_cast<const float4*>(feat + idx + 8);
            const float4 v3 = *reinterpret_cast<const float4*>(feat + idx + 12);
            union { ushort4 u4[2]; uint4 u; } o01, o23;
            o01.u4[0].x = f2bf(v0.x); o01.u4[0].y = f2bf(v0.y);
            o01.u4[0].z = f2bf(v0.z); o01.u4[0].w = f2bf(v0.w);
            o01.u4[1].x = f2bf(v1.x); o01.u4[1].y = f2bf(v1.y);
            o01.u4[1].z = f2bf(v1.z); o01.u4[1].w = f2bf(v1.w);
            o23.u4[0].x = f2bf(v2.x); o23.u4[0].y = f2bf(v2.y);
            o23.u4[0].z = f2bf(v2.z); o23.u4[0].w = f2bf(v2.w);
            o23.u4[1].x = f2bf(v3.x); o23.u4[1].y = f2bf(v3.y);
            o23.u4[1].z = f2bf(v3.z); o23.u4[1].w = f2bf(v3.w);
            *reinterpret_cast<uint4*>(h + idx) = o01.u;
            *reinterpret_cast<uint4*>(h + idx + 8) = o23.u;
        }
        return;
    }
    b -= CAST_BLKS;
    if (b < G0_DB) {
        fin_dst<G0_DB, 2>(sortD0, cntD0, offD0, nA0, b, esrc0, cnt0, sh.d.tile, sh.d.rowc);
    } else if (b < G0_DB + G1_DB) {
        fin_dst<G1_DB, 16>(sortD1, cntD1, offD1, nA1, b - G0_DB, esrc1, cnt1,
                           sh.d.tile, sh.d.rowc);
    } else if (b < G0_DB + G1_DB + G0_SB) {
        fin_src<G0_SB, G0_SW, 2>(sortS0, cntS0, offS0, nA0, b - G0_DB - G1_DB,
                                 100000, nv0, sh.hist);
    } else {
        fin_src<G1_SB, G1_SW, 16>(sortS1, cntS1, offS1, nA1, b - G0_DB - G1_DB - G0_SB,
                                  20000, nv1, sh.hist);
    }
}

// ---- gather ONE row per wave into LDS tile row rloc (halves the serial
// chain per wave, doubles wave count — latency-bound phase). unroll-8. ----
template <bool NORM>
static __device__ __forceinline__ void gather1_to_lds(
        const unsigned short* __restrict__ hfeat, const int* __restrict__ esrc,
        const int* __restrict__ cnt, const float* __restrict__ nv,
        int row, int rloc, int lane, unsigned short (*Alds)[264]) {
    const int c = cnt[row];
    const int cend = min(c, RSTRIDE);
    const int* __restrict__ ep = esrc + ((size_t)row << 7);
    float a0 = 0.f, a1 = 0.f, a2 = 0.f, a3 = 0.f;
    int i = 0;
    for (; i + 7 < cend; i += 8) {
        int s[8];
        uint2 p[8];
        float nn[8];
#pragma unroll
        for (int u = 0; u < 8; ++u) s[u] = ep[i + u];
#pragma unroll
        for (int u = 0; u < 8; ++u)
            p[u] = *reinterpret_cast<const uint2*>(hfeat + (((size_t)s[u]) << 8) + lane * 4);
#pragma unroll
        for (int u = 0; u < 8; ++u)
            nn[u] = NORM ? nv[s[u]] : 1.0f;
#pragma unroll
        for (int u = 0; u < 8; ++u) {
            if (NORM) {
                a0 = fmaf(bflo(p[u].x), nn[u], a0); a1 = fmaf(bfhi(p[u].x), nn[u], a1);
                a2 = fmaf(bflo(p[u].y), nn[u], a2); a3 = fmaf(bfhi(p[u].y), nn[u], a3);
            } else {
                a0 += bflo(p[u].x); a1 += bfhi(p[u].x);
                a2 += bflo(p[u].y); a3 += bfhi(p[u].y);
            }
        }
    }
    for (; i < cend; ++i) {
        int s0 = ep[i];
        float n0 = NORM ? nv[s0] : 1.0f;
        const uint2 p0 = *reinterpret_cast<const uint2*>(hfeat + (((size_t)s0) << 8) + lane * 4);
        if (NORM) {
            a0 = fmaf(bflo(p0.x), n0, a0); a1 = fmaf(bfhi(p0.x), n0, a1);
            a2 = fmaf(bflo(p0.y), n0, a2); a3 = fmaf(bfhi(p0.y), n0, a3);
        } else {
            a0 += bflo(p0.x); a1 += bfhi(p0.x);
            a2 += bflo(p0.y); a3 += bfhi(p0.y);
        }
    }
    float nd = rsqrtf((float)max(c, 1));
    ushort4 o;
    o.x = f2bf(a0 * nd);
    o.y = f2bf(a1 * nd);
    o.z = f2bf(a2 * nd);
    o.w = f2bf(a3 * nd);
    *reinterpret_cast<ushort4*>(&Alds[rloc][lane * 4]) = o;
}

// ---- fused layer 0 (1024 thr / 16 waves, 1 row/wave): gather -> LDS ->
// MFMA (16 waves x 1 col-tile = 256 cols) -> relu*nv1 -> bf16 ----
__global__ __launch_bounds__(1024, 4) void fused0_kernel(
        const unsigned short* __restrict__ hfeat, const int* __restrict__ esrc,
        const int* __restrict__ cnt, const float* __restrict__ nv0,
        const uint4* __restrict__ pW, const float* __restrict__ bias,
        const float* __restrict__ nv1, unsigned short* __restrict__ out) {
    __shared__ unsigned short Alds[16][264];
    const int m0 = blockIdx.x * 16;
    const int w = threadIdx.x >> 6;        // 0..15
    const int lane = threadIdx.x & 63;
    gather1_to_lds<true>(hfeat, esrc, cnt, nv0, m0 + w, w, lane, Alds);
    __syncthreads();

    bf16x8 a[8];
    const unsigned short* ap = &Alds[lane & 15][(lane >> 4) * 8];
#pragma unroll
    for (int kt = 0; kt < 8; ++kt)
        a[kt] = *reinterpret_cast<const bf16x8*>(ap + kt * 32);

    const int rbase = m0 + (lane >> 4) * 4;
    float nsv[4];
#pragma unroll
    for (int r = 0; r < 4; ++r) nsv[r] = nv1[rbase + r];

    const int n0 = w * 16;                 // 16 waves x 1 tile = 256 cols
    f32x4 acc = {0.f, 0.f, 0.f, 0.f};
#pragma unroll
    for (int kt = 0; kt < 8; ++kt) {
        bf16x8 b = *reinterpret_cast<const bf16x8*>(&pW[((size_t)(n0 >> 4) * 8 + kt) * 64 + lane]);
        acc = __builtin_amdgcn_mfma_f32_16x16x32_bf16(a[kt], b, acc, 0, 0, 0);
    }
    const int col = n0 + (lane & 15);
    const float bv = bias[col];
#pragma unroll
    for (int r = 0; r < 4; ++r) {
        float v = fmaxf(acc[r] + bv, 0.0f) * nsv[r];
        out[(size_t)(rbase + r) * K_DIM + col] = f2bf(v);
    }
}

// ---- fused layer 1 (1024 thr / 16 waves, 1 row/wave): gather -> LDS ->
// MFMA (waves 0-7 x 1 col-tile = 128 cols) -> +bias -> f32 ----
__global__ __launch_bounds__(1024, 4) void fused1_kernel(
        const unsigned short* __restrict__ xb, const int* __restrict__ esrc,
        const int* __restrict__ cnt,
        const uint4* __restrict__ pW, const float* __restrict__ bias,
        float* __restrict__ out) {
    __shared__ unsigned short Alds[16][264];
    const int m0 = blockIdx.x * 16;
    const int w = threadIdx.x >> 6;
    const int lane = threadIdx.x & 63;
    gather1_to_lds<false>(xb, esrc, cnt, nullptr, m0 + w, w, lane, Alds);
    __syncthreads();

    if (w < 8) {
        bf16x8 a[8];
        const unsigned short* ap = &Alds[lane & 15][(lane >> 4) * 8];
#pragma unroll
        for (int kt = 0; kt < 8; ++kt)
            a[kt] = *reinterpret_cast<const bf16x8*>(ap + kt * 32);

        const int rbase = m0 + (lane >> 4) * 4;
        const int n0 = w * 16;             // waves 0-7 -> cols 0..127
        f32x4 acc = {0.f, 0.f, 0.f, 0.f};
#pragma unroll
        for (int kt = 0; kt < 8; ++kt) {
            bf16x8 b = *reinterpret_cast<const bf16x8*>(&pW[((size_t)(n0 >> 4) * 8 + kt) * 64 + lane]);
            acc = __builtin_amdgcn_mfma_f32_16x16x32_bf16(a[kt], b, acc, 0, 0, 0);
        }
        const int col = n0 + (lane & 15);
        const float bv = bias[col];
#pragma unroll
        for (int r = 0; r < 4; ++r)
            out[(size_t)(rbase + r) * 128 + col] = acc[r] + bv;
    }
}

// ================= fp32 fallback path (ws too small) =================
__global__ __launch_bounds__(256) void gatherf_kernel(
        const float* __restrict__ feat, const int* __restrict__ esrc,
        const int* __restrict__ cnt, const int* __restrict__ od,
        float* __restrict__ outbuf, int n_dst) {
    int row = blockIdx.x * (blockDim.x >> 6) + (threadIdx.x >> 6);
    int lane = threadIdx.x & 63;
    if (row >= n_dst) return;
    const int c = cnt[row];
    const int cend = min(c, RSTRIDE);
    const int* __restrict__ ep = esrc + ((size_t)row << 7);
    float4 acc = {0.f, 0.f, 0.f, 0.f};
    for (int i = 0; i < cend; ++i) {
        int s0 = ep[i];
        float n0 = rsqrtf((float)max(od[s0], 1));
        const float4 v0 = *reinterpret_cast<const float4*>(feat + (((size_t)s0) << 8) + lane * 4);
        acc.x = fmaf(v0.x, n0, acc.x); acc.y = fmaf(v0.y, n0, acc.y);
        acc.z = fmaf(v0.z, n0, acc.z); acc.w = fmaf(v0.w, n0, acc.w);
    }
    float nd = rsqrtf((float)max(c, 1));
    float4 o = {acc.x * nd, acc.y * nd, acc.z * nd, acc.w * nd};
    *reinterpret_cast<float4*>(outbuf + (((size_t)row) << 8) + lane * 4) = o;
}

__global__ void edges_kernel(const int* __restrict__ src0, const int* __restrict__ dst0,
                             int* __restrict__ od0, int* __restrict__ cnt0,
                             int* __restrict__ esrc0, int E0,
                             const int* __restrict__ src1, const int* __restrict__ dst1,
                             int* __restrict__ od1, int* __restrict__ cnt1,
                             int* __restrict__ esrc1, int E1) {
    int i = blockIdx.x * blockDim.x + threadIdx.x;
    if (i < E0) {
        int s = src0[i];
        int d = dst0[i];
        atomicAdd(&od0[s], 1);
        int slot = atomicAdd(&cnt0[d], 1);
        if (slot < RSTRIDE) esrc0[(d << 7) + slot] = s;
    } else if (i < E0 + E1) {
        int e = i - E0;
        int s = src1[e];
        int d = dst1[e];
        atomicAdd(&od1[s], 1);
        int slot = atomicAdd(&cnt1[d], 1);
        if (slot < RSTRIDE) esrc1[(d << 7) + slot] = s;
    }
}

template <int ROWS, int NCOLS, bool RELU>
__global__ __launch_bounds__(NCOLS) void gemm_kernel(
        const float* __restrict__ A, const float* __restrict__ W,
        const float* __restrict__ bias, float* __restrict__ out, int M) {
    const int row0 = blockIdx.x * ROWS;
    const int c = threadIdx.x;
    const float* __restrict__ Ablk = A + (size_t)row0 * K_DIM;
    const float* __restrict__ Wc = W + c;

    float acc[ROWS];
#pragma unroll
    for (int r = 0; r < ROWS; ++r) acc[r] = 0.0f;

    float w0 = Wc[0];
    float w1 = Wc[NCOLS];
    float w2 = Wc[2 * NCOLS];
    float w3 = Wc[3 * NCOLS];

#pragma unroll 2
    for (int k = 0; k < K_DIM - 4; k += 4) {
        const float* p = Wc + (size_t)(k + 4) * NCOLS;
        float n0 = p[0];
        float n1 = p[NCOLS];
        float n2 = p[2 * NCOLS];
        float n3 = p[3 * NCOLS];
#pragma unroll
        for (int r = 0; r < ROWS; ++r) {
            const float4 a = *reinterpret_cast<const float4*>(Ablk + r * K_DIM + k);
            acc[r] = fmaf(a.x, w0, acc[r]);
            acc[r] = fmaf(a.y, w1, acc[r]);
            acc[r] = fmaf(a.z, w2, acc[r]);
            acc[r] = fmaf(a.w, w3, acc[r]);
        }
        w0 = n0; w1 = n1; w2 = n2; w3 = n3;
    }
    {
        const int k = K_DIM - 4;
#pragma unroll
        for (int r = 0; r < ROWS; ++r) {
            const float4 a = *reinterpret_cast<const float4*>(Ablk + r * K_DIM + k);
            acc[r] = fmaf(a.x, w0, acc[r]);
            acc[r] = fmaf(a.y, w1, acc[r]);
            acc[r] = fmaf(a.z, w2, acc[r]);
            acc[r] = fmaf(a.w, w3, acc[r]);
        }
    }

    const float b = bias[c];
#pragma unroll
    for (int r = 0; r < ROWS; ++r) {
        float v = acc[r] + b;
        if (RELU) v = fmaxf(v, 0.0f);
        out[(size_t)(row0 + r) * NCOLS + c] = v;
    }
}

extern "C" void kernel_launch(void* const* d_in, const int* in_sizes, int n_in,
                              void* d_out, int out_size, void* d_ws, size_t ws_size,
                              hipStream_t stream) {
    const float* features = (const float*)d_in[0];
    const float* W1 = (const float*)d_in[1];
    const float* b1 = (const float*)d_in[2];
    const float* W2 = (const float*)d_in[3];
    const float* b2 = (const float*)d_in[4];
    const int* src0 = (const int*)d_in[5];
    const int* dst0 = (const int*)d_in[6];
    const int* src1 = (const int*)d_in[7];
    const int* dst1 = (const int*)d_in[8];
    const int E0 = in_sizes[5];
    const int E1 = in_sizes[7];
    const int NSRC0 = 100000, NDST0 = 20000, NDST1 = 4096;
    const int nA0 = (E0 + EPB - 1) / EPB;                      // 79
    const int nA1 = (E1 + EPB - 1) / EPB;                      // 16

    char* ws = (char*)d_ws;
    size_t off = 0;
    auto carve = [&](size_t bytes) -> void* {
        void* p = ws + off;
        off = (off + bytes + 255) & ~(size_t)255;
        return p;
    };
    // dense tables (bf16 path: fully written by castfin, NO memset needed;
    // fp32 fallback memsets [0, zero_span)). od buffers double as f32 norm
    // tables on the bf16 path (exclusive paths).
    int* od0  = (int*)carve((size_t)NSRC0 * 4);
    int* od1  = (int*)carve((size_t)NDST0 * 4);
    int* cnt0 = (int*)carve((size_t)NDST0 * 4);
    int* cnt1 = (int*)carve((size_t)NDST1 * 4);
    const size_t zero_span = off;
    int* esrc0p = (int*)carve((size_t)NDST0 * RSTRIDE * 4);
    int* esrc1p = (int*)carve((size_t)NDST1 * RSTRIDE * 4);
    uint4* pW1  = (uint4*)carve((size_t)8192 * 16);
    uint4* pW2  = (uint4*)carve((size_t)4096 * 16);
    int* cntD0 = (int*)carve((size_t)nA0 * G0_DB * 4);
    int* offD0 = (int*)carve((size_t)nA0 * G0_DB * 4);
    int* cntS0 = (int*)carve((size_t)nA0 * G0_SB * 4);
    int* offS0 = (int*)carve((size_t)nA0 * G0_SB * 4);
    int* cntD1 = (int*)carve((size_t)nA1 * G1_DB * 4);
    int* offD1 = (int*)carve((size_t)nA1 * G1_DB * 4);
    int* cntS1 = (int*)carve((size_t)nA1 * G1_SB * 4);
    int* offS1 = (int*)carve((size_t)nA1 * G1_SB * 4);
    unsigned* sortD0 = (unsigned*)carve((size_t)nA0 * EPB * 4);
    unsigned* sortS0 = (unsigned*)carve((size_t)nA0 * EPB * 4);
    unsigned* sortD1 = (unsigned*)carve((size_t)nA1 * EPB * 4);
    unsigned* sortS1 = (unsigned*)carve((size_t)nA1 * EPB * 4);
    unsigned short* xbufb = (unsigned short*)carve((size_t)NDST0 * K_DIM * 2);
    unsigned short* hfeat = (unsigned short*)carve((size_t)NSRC0 * K_DIM * 2);
    const size_t need_bf16 = off;
    (void)n_in; (void)out_size;

    if (ws_size >= need_bf16) {
        float* nv0 = (float*)od0;                              // f32 norm tables
        float* nv1 = (float*)od1;
        const int numVec16 = NSRC0 * K_DIM / 16;               // 1.6M 16-float vectors
        splitA_kernel<<<nA0 + nA1 + 48, 256, 0, stream>>>(
            src0, dst0, E0, src1, dst1, E1,
            cntD0, offD0, cntS0, offS0, sortD0, sortS0,
            cntD1, offD1, cntS1, offS1, sortD1, sortS1,
            nA0, nA1, W1, pW1, W2, pW2);
        castfin_kernel<<<CAST_BLKS + NB_FIN, 256, 0, stream>>>(
            nA0, nA1,
            sortD0, cntD0, offD0, cnt0, esrc0p,
            sortD1, cntD1, offD1, cnt1, esrc1p,
            sortS0, cntS0, offS0, nv0,
            sortS1, cntS1, offS1, nv1,
            features, hfeat, numVec16);
        fused0_kernel<<<NDST0 / 16, 1024, 0, stream>>>(
            hfeat, esrc0p, cnt0, nv0, pW1, b1, nv1, xbufb);
        fused1_kernel<<<NDST1 / 16, 1024, 0, stream>>>(
            xbufb, esrc1p, cnt1, pW2, b2, (float*)d_out);
    } else {
        // fp32 fallback: direct atomics on dense tables
        hipMemsetAsync(ws, 0, zero_span, stream);
        float* agg0 = (float*)carve((size_t)NDST0 * K_DIM * 4);
        float* xbuf = (float*)carve((size_t)NDST0 * K_DIM * 4);
        float* agg1 = (float*)carve((size_t)NDST1 * K_DIM * 4);
        edges_kernel<<<(E0 + E1 + 255) / 256, 256, 0, stream>>>(
            src0, dst0, od0, cnt0, esrc0p, E0,
            src1, dst1, od1, cnt1, esrc1p, E1);
        gatherf_kernel<<<(NDST0 + 3) / 4, 256, 0, stream>>>(features, esrc0p, cnt0, od0,
                                                            agg0, NDST0);
        gemm_kernel<16, 256, true><<<NDST0 / 16, 256, 0, stream>>>(agg0, W1, b1, xbuf, NDST0);
        gatherf_kernel<<<(NDST1 + 3) / 4, 256, 0, stream>>>(xbuf, esrc1p, cnt1, od1,
                                                            agg1, NDST1);
        gemm_kernel<4, 128, false><<<NDST1 / 4, 128, 0, stream>>>(agg1, W2, b2,
                                                                  (float*)d_out, NDST1);
    }
}

// Round 11
// 270.811 us; speedup vs baseline: 1.0895x; 1.0895x over previous
//
#include <hip/hip_runtime.h>
#include <hip/hip_bf16.h>

#define K_DIM 256
#define RSTRIDE 128   // padded CSR row stride; in-deg max ~58 (Binomial mean 32), 2x margin
#define EPB 4096      // edges per split chunk (sorted buffer 16 KB LDS -> 7 blocks/CU)

// bucket geometry (bucket = 32 dst rows for CSR build; src buckets for out-degree)
#define G0_DB 625     // graph0 dst buckets (625*32 = 20000)
#define G0_SB 256     // graph0 src buckets
#define G0_SW 392     // nodes per src bucket (256*392 >= 100000)
#define G0_GDIV 12500 // src-octant width for grouped CSR rows (100000/8)
#define G1_DB 128     // graph1 dst buckets (128*32 = 4096)
#define G1_SB 64
#define G1_SW 313     // 64*313 >= 20000
#define G1_GDIV 2500  // 20000/8

#define NB_FIN (G0_DB + G1_DB + G0_SB + G1_SB)   // 1073 finalize jobs

typedef short bf16x8 __attribute__((ext_vector_type(8)));
typedef float f32x4 __attribute__((ext_vector_type(4)));

static __device__ __forceinline__ unsigned short f2bf(float x) {
    __hip_bfloat16 b = __float2bfloat16(x);   // RNE
    return *reinterpret_cast<unsigned short*>(&b);
}
static __device__ __forceinline__ float bflo(unsigned int p) {
    return __uint_as_float(p << 16);
}
static __device__ __forceinline__ float bfhi(unsigned int p) {
    return __uint_as_float(p & 0xffff0000u);
}

// ---- block-wide exclusive scan of hist[0..M) -> offs[0..M) (tmp[256]) ----
static __device__ __forceinline__ void block_exscan(
        const int* __restrict__ hist, int* __restrict__ offs, int* __restrict__ tmp, int M) {
    const int tid = threadIdx.x;
    const int S = (M + 255) >> 8;        // strip length per thread
    const int base = tid * S;
    int sum = 0;
    for (int k = 0; k < S; ++k) {
        int idx = base + k;
        if (idx < M) sum += hist[idx];
    }
    tmp[tid] = sum;
    __syncthreads();
    // Hillis-Steele inclusive scan over 256 strip sums
    for (int d = 1; d < 256; d <<= 1) {
        int v = tmp[tid];
        int u = (tid >= d) ? tmp[tid - d] : 0;
        __syncthreads();
        tmp[tid] = v + u;
        __syncthreads();
    }
    int run = (tid == 0) ? 0 : tmp[tid - 1];
    for (int k = 0; k < S; ++k) {
        int idx = base + k;
        if (idx < M) { offs[idx] = run; run += hist[idx]; }
    }
    __syncthreads();
}

struct SplitSh {
    int hist[640];
    int offs[640];
    int tmp[256];
    unsigned sorted[EPB];
};  // 22.5 KB -> 7 blocks/CU (R11: was 38.9 KB / 4 blocks — throttled the fused cast)

// ---- per-chunk LDS counting sort, BOTH keys, all-coalesced global writes ----
template <int NDB, int NSB, int SW>
static __device__ __forceinline__ void split_sort(
        const int* __restrict__ src, const int* __restrict__ dst, int E, int chunk,
        int* __restrict__ cntD, int* __restrict__ offD,
        int* __restrict__ cntS, int* __restrict__ offS,
        unsigned* __restrict__ sortD, unsigned* __restrict__ sortS, SplitSh& sh) {
    const int tid = threadIdx.x;
    const int e0 = chunk * EPB;
    const int n = min(EPB, E - e0);
    // ---------- dst key ----------
    for (int i = tid; i < NDB; i += 256) sh.hist[i] = 0;
    __syncthreads();
    for (int j = tid; j < n; j += 256) atomicAdd(&sh.hist[dst[e0 + j] >> 5], 1);
    __syncthreads();
    block_exscan(sh.hist, sh.offs, sh.tmp, NDB);
    for (int i = tid; i < NDB; i += 256) {
        cntD[chunk * NDB + i] = sh.hist[i];
        offD[chunk * NDB + i] = sh.offs[i];
    }
    __syncthreads();
    for (int j = tid; j < n; j += 256) {
        int d = dst[e0 + j];
        int s = src[e0 + j];
        int pos = atomicAdd(&sh.offs[d >> 5], 1);        // LDS cursor; pos < n always
        sh.sorted[pos] = ((unsigned)s << 5) | (unsigned)(d & 31);
    }
    __syncthreads();
    {
        unsigned* __restrict__ gout = sortD + (size_t)chunk * EPB;
        for (int j = tid; j < n; j += 256) gout[j] = sh.sorted[j];   // coalesced
    }
    __syncthreads();
    // ---------- src key ----------
    for (int i = tid; i < NSB; i += 256) sh.hist[i] = 0;
    __syncthreads();
    for (int j = tid; j < n; j += 256)
        atomicAdd(&sh.hist[(int)((unsigned)src[e0 + j] / SW)], 1);
    __syncthreads();
    block_exscan(sh.hist, sh.offs, sh.tmp, NSB);
    for (int i = tid; i < NSB; i += 256) {
        cntS[chunk * NSB + i] = sh.hist[i];
        offS[chunk * NSB + i] = sh.offs[i];
    }
    __syncthreads();
    for (int j = tid; j < n; j += 256) {
        unsigned s = (unsigned)src[e0 + j];
        int pos = atomicAdd(&sh.offs[s / SW], 1);
        sh.sorted[pos] = s;
    }
    __syncthreads();
    {
        unsigned* __restrict__ gout = sortS + (size_t)chunk * EPB;
        for (int j = tid; j < n; j += 256) gout[j] = sh.sorted[j];   // coalesced
    }
}

// ---- MEGA splitA (R6 structure): edge sort + feature cast + weight packs.
// Sort blocks first (189 of 1792 resident slots); cast streams on the rest. ----
__global__ __launch_bounds__(256) void splitA_kernel(
        const int* __restrict__ src0, const int* __restrict__ dst0, int E0,
        const int* __restrict__ src1, const int* __restrict__ dst1, int E1,
        int* __restrict__ cntD0, int* __restrict__ offD0,
        int* __restrict__ cntS0, int* __restrict__ offS0,
        unsigned* __restrict__ sortD0, unsigned* __restrict__ sortS0,
        int* __restrict__ cntD1, int* __restrict__ offD1,
        int* __restrict__ cntS1, int* __restrict__ offS1,
        unsigned* __restrict__ sortD1, unsigned* __restrict__ sortS1,
        int nA0, int nA1,
        const float* __restrict__ feat, unsigned short* __restrict__ h, int total_f,
        int castBlocks,
        const float* __restrict__ W1, uint4* __restrict__ pw1,
        const float* __restrict__ W2, uint4* __restrict__ pw2) {
    __shared__ SplitSh sh;
    const int b = blockIdx.x;
    if (b < nA0) {
        split_sort<G0_DB, G0_SB, G0_SW>(src0, dst0, E0, b,
                                        cntD0, offD0, cntS0, offS0, sortD0, sortS0, sh);
    } else if (b < nA0 + nA1) {
        split_sort<G1_DB, G1_SB, G1_SW>(src1, dst1, E1, b - nA0,
                                        cntD1, offD1, cntS1, offS1, sortD1, sortS1, sh);
    } else if (b < nA0 + nA1 + castBlocks) {
        int idx = ((b - nA0 - nA1) * blockDim.x + threadIdx.x) * 8;
        if (idx >= total_f) return;
        const float4 v0 = *reinterpret_cast<const float4*>(feat + idx);
        const float4 v1 = *reinterpret_cast<const float4*>(feat + idx + 4);
        union { ushort4 u4[2]; uint4 u; } o;
        o.u4[0].x = f2bf(v0.x); o.u4[0].y = f2bf(v0.y);
        o.u4[0].z = f2bf(v0.z); o.u4[0].w = f2bf(v0.w);
        o.u4[1].x = f2bf(v1.x); o.u4[1].y = f2bf(v1.y);
        o.u4[1].z = f2bf(v1.z); o.u4[1].w = f2bf(v1.w);
        *reinterpret_cast<uint4*>(h + idx) = o.u;
    } else if (b < nA0 + nA1 + castBlocks + 32) {
        // pack W1 (256x256 f32 [k][n]) -> bf16 B-frag layout:
        // pw[(nt*8+kt)*64+lane] = W[kt*32+(lane>>4)*8+j][nt*16+(lane&15)], j=0..7
        int idx = (b - nA0 - nA1 - castBlocks) * blockDim.x + threadIdx.x;   // 0..8191
        int lane = idx & 63;
        int kt = (idx >> 6) & 7;
        int nt = idx >> 9;
        int n = nt * 16 + (lane & 15);
        int k = kt * 32 + (lane >> 4) * 8;
        union { unsigned short us[8]; uint4 u; } o;
#pragma unroll
        for (int j = 0; j < 8; ++j) o.us[j] = f2bf(W1[(size_t)(k + j) * 256 + n]);
        pw1[idx] = o.u;
    } else {
        int idx = (b - nA0 - nA1 - castBlocks - 32) * blockDim.x + threadIdx.x; // 0..4095
        int lane = idx & 63;
        int kt = (idx >> 6) & 7;
        int nt = idx >> 9;
        int n = nt * 16 + (lane & 15);
        int k = kt * 32 + (lane >> 4) * 8;
        union { unsigned short us[8]; uint4 u; } o;
#pragma unroll
        for (int j = 0; j < 8; ++j) o.us[j] = f2bf(W2[(size_t)(k + j) * 128 + n]);
        pw2[idx] = o.u;
    }
}

// ---- finalize dst-bucket (R11): build each CSR row GROUPED BY ASCENDING
// SRC-OCTANT (2-pass LDS counting scatter over the tiny L2-warm segments).
// fused0 then sweeps src-space in loosely aligned phases: instantaneous
// working set ~6.4 MB -> L2/L3-resident instead of 51.2 MB random. ----
template <int NDB, int GT, int GDIV>
static __device__ __forceinline__ void fin_dst(
        const unsigned* __restrict__ sortD, const int* __restrict__ cntD,
        const int* __restrict__ offD, int nblk, int b,
        int* __restrict__ esrc, int* __restrict__ cnt,
        int* tile, int* gcur, int* gtot) {
    const int tid = threadIdx.x;
    for (int i = tid; i < 256; i += 256) gcur[i] = 0;
    __syncthreads();
    // pass 1: histogram per (row, src-octant)
    for (int rr = tid / GT; rr < nblk; rr += 256 / GT) {
        const int c = cntD[rr * NDB + b];
        const int o = offD[rr * NDB + b];
        const unsigned* __restrict__ seg = sortD + (size_t)rr * EPB + o;
        for (int j = tid % GT; j < c; j += GT) {
            unsigned v = seg[j];
            atomicAdd(&gcur[((v & 31) << 3) + (int)((v >> 5) / GDIV)], 1);
        }
    }
    __syncthreads();
    // per-row prefix over 8 octants; total -> gtot
    if (tid < 32) {
        int run = 0;
#pragma unroll
        for (int g = 0; g < 8; ++g) {
            int hh = gcur[(tid << 3) + g];
            gcur[(tid << 3) + g] = run;
            run += hh;
        }
        gtot[tid] = run;
    }
    __syncthreads();
    // pass 2: grouped scatter
    for (int rr = tid / GT; rr < nblk; rr += 256 / GT) {
        const int c = cntD[rr * NDB + b];
        const int o = offD[rr * NDB + b];
        const unsigned* __restrict__ seg = sortD + (size_t)rr * EPB + o;
        for (int j = tid % GT; j < c; j += GT) {
            unsigned v = seg[j];
            int dloc = v & 31;
            int s = (int)(v >> 5);
            int slot = atomicAdd(&gcur[(dloc << 3) + (int)((unsigned)s / GDIV)], 1);
            if (slot < RSTRIDE) tile[(dloc << 7) + slot] = s;
        }
    }
    __syncthreads();
    // coalesced 16 KB stream: tile layout == global padded-CSR layout
    int* __restrict__ gout = esrc + ((size_t)b << 12);
    for (int i = tid; i < 32 * RSTRIDE; i += 256) gout[i] = tile[i];
    if (tid < 32) cnt[b * 32 + tid] = gtot[tid];   // true (uncapped) in-degree
}

// ---- finalize src-bucket: out-degree histogram -> f32 norm table ----
template <int NSB, int SW, int GT>
static __device__ __forceinline__ void fin_src(
        const unsigned* __restrict__ sortS, const int* __restrict__ cntS,
        const int* __restrict__ offS, int nblk, int b, int NN,
        float* __restrict__ nv, int* hist) {
    const int tid = threadIdx.x;
    for (int i = tid; i < SW; i += 256) hist[i] = 0;
    __syncthreads();
    const int base = b * SW;
    for (int rr = tid / GT; rr < nblk; rr += 256 / GT) {
        const int c = cntS[rr * NSB + b];
        const int o = offS[rr * NSB + b];
        const unsigned* __restrict__ seg = sortS + (size_t)rr * EPB + o;
        for (int j = tid % GT; j < c; j += GT)
            atomicAdd(&hist[(int)seg[j] - base], 1);
    }
    __syncthreads();
    for (int i = tid; i < SW; i += 256) {
        int node = base + i;
        if (node < NN) nv[node] = rsqrtf((float)max(hist[i], 1));   // dense write
    }
}

__global__ __launch_bounds__(256) void finalize_kernel(
        int nA0, int nA1,
        const unsigned* __restrict__ sortD0, const int* __restrict__ cntD0,
        const int* __restrict__ offD0, int* __restrict__ cnt0, int* __restrict__ esrc0,
        const unsigned* __restrict__ sortD1, const int* __restrict__ cntD1,
        const int* __restrict__ offD1, int* __restrict__ cnt1, int* __restrict__ esrc1,
        const unsigned* __restrict__ sortS0, const int* __restrict__ cntS0,
        const int* __restrict__ offS0, float* __restrict__ nv0,
        const unsigned* __restrict__ sortS1, const int* __restrict__ cntS1,
        const int* __restrict__ offS1, float* __restrict__ nv1) {
    __shared__ union {
        struct { int tile[32 * RSTRIDE]; int gcur[256]; int gtot[32]; } d;  // 17.5 KB
        int hist[G0_SW];
    } sh;
    int b = blockIdx.x;
    if (b < G0_DB) {
        fin_dst<G0_DB, 2, G0_GDIV>(sortD0, cntD0, offD0, nA0, b, esrc0, cnt0,
                                   sh.d.tile, sh.d.gcur, sh.d.gtot);
    } else if (b < G0_DB + G1_DB) {
        fin_dst<G1_DB, 8, G1_GDIV>(sortD1, cntD1, offD1, nA1, b - G0_DB, esrc1, cnt1,
                                   sh.d.tile, sh.d.gcur, sh.d.gtot);
    } else if (b < G0_DB + G1_DB + G0_SB) {
        fin_src<G0_SB, G0_SW, 2>(sortS0, cntS0, offS0, nA0, b - G0_DB - G1_DB,
                                 100000, nv0, sh.hist);
    } else {
        fin_src<G1_SB, G1_SW, 8>(sortS1, cntS1, offS1, nA1, b - G0_DB - G1_DB - G0_SB,
                                 20000, nv1, sh.hist);
    }
}

// ---- gather 16 rows (2 per wave, 8 waves) into LDS bf16 tile [16][264],
// unroll-8, norm via f32 table load (no per-edge rsqrt). R8-proven config. ----
template <bool NORM>
static __device__ __forceinline__ void gather2_to_lds(
        const unsigned short* __restrict__ hfeat, const int* __restrict__ esrc,
        const int* __restrict__ cnt, const float* __restrict__ nv,
        int m0, int w, int lane, unsigned short (*Alds)[264]) {
#pragma unroll
    for (int k = 0; k < 2; ++k) {
        const int rloc = w * 2 + k;
        const int row = m0 + rloc;
        const int c = cnt[row];
        const int cend = min(c, RSTRIDE);
        const int* __restrict__ ep = esrc + ((size_t)row << 7);
        float a0 = 0.f, a1 = 0.f, a2 = 0.f, a3 = 0.f;
        int i = 0;
        for (; i + 7 < cend; i += 8) {
            int s[8];
            uint2 p[8];
            float nn[8];
#pragma unroll
            for (int u = 0; u < 8; ++u) s[u] = ep[i + u];
#pragma unroll
            for (int u = 0; u < 8; ++u)
                p[u] = *reinterpret_cast<const uint2*>(hfeat + (((size_t)s[u]) << 8) + lane * 4);
#pragma unroll
            for (int u = 0; u < 8; ++u)
                nn[u] = NORM ? nv[s[u]] : 1.0f;
#pragma unroll
            for (int u = 0; u < 8; ++u) {
                if (NORM) {
                    a0 = fmaf(bflo(p[u].x), nn[u], a0); a1 = fmaf(bfhi(p[u].x), nn[u], a1);
                    a2 = fmaf(bflo(p[u].y), nn[u], a2); a3 = fmaf(bfhi(p[u].y), nn[u], a3);
                } else {
                    a0 += bflo(p[u].x); a1 += bfhi(p[u].x);
                    a2 += bflo(p[u].y); a3 += bfhi(p[u].y);
                }
            }
        }
        for (; i < cend; ++i) {
            int s0 = ep[i];
            float n0 = NORM ? nv[s0] : 1.0f;
            const uint2 p0 = *reinterpret_cast<const uint2*>(hfeat + (((size_t)s0) << 8) + lane * 4);
            if (NORM) {
                a0 = fmaf(bflo(p0.x), n0, a0); a1 = fmaf(bfhi(p0.x), n0, a1);
                a2 = fmaf(bflo(p0.y), n0, a2); a3 = fmaf(bfhi(p0.y), n0, a3);
            } else {
                a0 += bflo(p0.x); a1 += bfhi(p0.x);
                a2 += bflo(p0.y); a3 += bfhi(p0.y);
            }
        }
        float nd = rsqrtf((float)max(c, 1));
        ushort4 o;
        o.x = f2bf(a0 * nd);
        o.y = f2bf(a1 * nd);
        o.z = f2bf(a2 * nd);
        o.w = f2bf(a3 * nd);
        *reinterpret_cast<ushort4*>(&Alds[rloc][lane * 4]) = o;
    }
}

// ---- fused layer 0 (512 thr / 8 waves): gather -> LDS -> MFMA -> relu*nv1 ----
__global__ __launch_bounds__(512, 8) void fused0_kernel(
        const unsigned short* __restrict__ hfeat, const int* __restrict__ esrc,
        const int* __restrict__ cnt, const float* __restrict__ nv0,
        const uint4* __restrict__ pW, const float* __restrict__ bias,
        const float* __restrict__ nv1, unsigned short* __restrict__ out) {
    __shared__ unsigned short Alds[16][264];
    const int m0 = blockIdx.x * 16;
    const int w = threadIdx.x >> 6;        // 0..7
    const int lane = threadIdx.x & 63;
    gather2_to_lds<true>(hfeat, esrc, cnt, nv0, m0, w, lane, Alds);
    __syncthreads();

    bf16x8 a[8];
    const unsigned short* ap = &Alds[lane & 15][(lane >> 4) * 8];
#pragma unroll
    for (int kt = 0; kt < 8; ++kt)
        a[kt] = *reinterpret_cast<const bf16x8*>(ap + kt * 32);

    const int rbase = m0 + (lane >> 4) * 4;
    float nsv[4];
#pragma unroll
    for (int r = 0; r < 4; ++r) nsv[r] = nv1[rbase + r];

#pragma unroll
    for (int nt = 0; nt < 2; ++nt) {                 // 8 waves x 2 tiles = 256 cols
        const int n0 = w * 32 + nt * 16;
        f32x4 acc = {0.f, 0.f, 0.f, 0.f};
#pragma unroll
        for (int kt = 0; kt < 8; ++kt) {
            bf16x8 b = *reinterpret_cast<const bf16x8*>(&pW[((size_t)(n0 >> 4) * 8 + kt) * 64 + lane]);
            acc = __builtin_amdgcn_mfma_f32_16x16x32_bf16(a[kt], b, acc, 0, 0, 0);
        }
        const int col = n0 + (lane & 15);
        const float bv = bias[col];
#pragma unroll
        for (int r = 0; r < 4; ++r) {
            float v = fmaxf(acc[r] + bv, 0.0f) * nsv[r];
            out[(size_t)(rbase + r) * K_DIM + col] = f2bf(v);
        }
    }
}

// ---- fused layer 1 (512 thr / 8 waves): gather -> LDS -> MFMA -> +bias f32 ----
__global__ __launch_bounds__(512, 8) void fused1_kernel(
        const unsigned short* __restrict__ xb, const int* __restrict__ esrc,
        const int* __restrict__ cnt,
        const uint4* __restrict__ pW, const float* __restrict__ bias,
        float* __restrict__ out) {
    __shared__ unsigned short Alds[16][264];
    const int m0 = blockIdx.x * 16;
    const int w = threadIdx.x >> 6;
    const int lane = threadIdx.x & 63;
    gather2_to_lds<false>(xb, esrc, cnt, nullptr, m0, w, lane, Alds);
    __syncthreads();

    bf16x8 a[8];
    const unsigned short* ap = &Alds[lane & 15][(lane >> 4) * 8];
#pragma unroll
    for (int kt = 0; kt < 8; ++kt)
        a[kt] = *reinterpret_cast<const bf16x8*>(ap + kt * 32);

    const int rbase = m0 + (lane >> 4) * 4;
    {
        const int n0 = w * 16;                       // 8 waves x 1 tile = 128 cols
        f32x4 acc = {0.f, 0.f, 0.f, 0.f};
#pragma unroll
        for (int kt = 0; kt < 8; ++kt) {
            bf16x8 b = *reinterpret_cast<const bf16x8*>(&pW[((size_t)(n0 >> 4) * 8 + kt) * 64 + lane]);
            acc = __builtin_amdgcn_mfma_f32_16x16x32_bf16(a[kt], b, acc, 0, 0, 0);
        }
        const int col = n0 + (lane & 15);
        const float bv = bias[col];
#pragma unroll
        for (int r = 0; r < 4; ++r)
            out[(size_t)(rbase + r) * 128 + col] = acc[r] + bv;
    }
}

// ================= fp32 fallback path (ws too small) =================
__global__ __launch_bounds__(256) void gatherf_kernel(
        const float* __restrict__ feat, const int* __restrict__ esrc,
        const int* __restrict__ cnt, const int* __restrict__ od,
        float* __restrict__ outbuf, int n_dst) {
    int row = blockIdx.x * (blockDim.x >> 6) + (threadIdx.x >> 6);
    int lane = threadIdx.x & 63;
    if (row >= n_dst) return;
    const int c = cnt[row];
    const int cend = min(c, RSTRIDE);
    const int* __restrict__ ep = esrc + ((size_t)row << 7);
    float4 acc = {0.f, 0.f, 0.f, 0.f};
    for (int i = 0; i < cend; ++i) {
        int s0 = ep[i];
        float n0 = rsqrtf((float)max(od[s0], 1));
        const float4 v0 = *reinterpret_cast<const float4*>(feat + (((size_t)s0) << 8) + lane * 4);
        acc.x = fmaf(v0.x, n0, acc.x); acc.y = fmaf(v0.y, n0, acc.y);
        acc.z = fmaf(v0.z, n0, acc.z); acc.w = fmaf(v0.w, n0, acc.w);
    }
    float nd = rsqrtf((float)max(c, 1));
    float4 o = {acc.x * nd, acc.y * nd, acc.z * nd, acc.w * nd};
    *reinterpret_cast<float4*>(outbuf + (((size_t)row) << 8) + lane * 4) = o;
}

__global__ void edges_kernel(const int* __restrict__ src0, const int* __restrict__ dst0,
                             int* __restrict__ od0, int* __restrict__ cnt0,
                             int* __restrict__ esrc0, int E0,
                             const int* __restrict__ src1, const int* __restrict__ dst1,
                             int* __restrict__ od1, int* __restrict__ cnt1,
                             int* __restrict__ esrc1, int E1) {
    int i = blockIdx.x * blockDim.x + threadIdx.x;
    if (i < E0) {
        int s = src0[i];
        int d = dst0[i];
        atomicAdd(&od0[s], 1);
        int slot = atomicAdd(&cnt0[d], 1);
        if (slot < RSTRIDE) esrc0[(d << 7) + slot] = s;
    } else if (i < E0 + E1) {
        int e = i - E0;
        int s = src1[e];
        int d = dst1[e];
        atomicAdd(&od1[s], 1);
        int slot = atomicAdd(&cnt1[d], 1);
        if (slot < RSTRIDE) esrc1[(d << 7) + slot] = s;
    }
}

template <int ROWS, int NCOLS, bool RELU>
__global__ __launch_bounds__(NCOLS) void gemm_kernel(
        const float* __restrict__ A, const float* __restrict__ W,
        const float* __restrict__ bias, float* __restrict__ out, int M) {
    const int row0 = blockIdx.x * ROWS;
    const int c = threadIdx.x;
    const float* __restrict__ Ablk = A + (size_t)row0 * K_DIM;
    const float* __restrict__ Wc = W + c;

    float acc[ROWS];
#pragma unroll
    for (int r = 0; r < ROWS; ++r) acc[r] = 0.0f;

    float w0 = Wc[0];
    float w1 = Wc[NCOLS];
    float w2 = Wc[2 * NCOLS];
    float w3 = Wc[3 * NCOLS];

#pragma unroll 2
    for (int k = 0; k < K_DIM - 4; k += 4) {
        const float* p = Wc + (size_t)(k + 4) * NCOLS;
        float n0 = p[0];
        float n1 = p[NCOLS];
        float n2 = p[2 * NCOLS];
        float n3 = p[3 * NCOLS];
#pragma unroll
        for (int r = 0; r < ROWS; ++r) {
            const float4 a = *reinterpret_cast<const float4*>(Ablk + r * K_DIM + k);
            acc[r] = fmaf(a.x, w0, acc[r]);
            acc[r] = fmaf(a.y, w1, acc[r]);
            acc[r] = fmaf(a.z, w2, acc[r]);
            acc[r] = fmaf(a.w, w3, acc[r]);
        }
        w0 = n0; w1 = n1; w2 = n2; w3 = n3;
    }
    {
        const int k = K_DIM - 4;
#pragma unroll
        for (int r = 0; r < ROWS; ++r) {
            const float4 a = *reinterpret_cast<const float4*>(Ablk + r * K_DIM + k);
            acc[r] = fmaf(a.x, w0, acc[r]);
            acc[r] = fmaf(a.y, w1, acc[r]);
            acc[r] = fmaf(a.z, w2, acc[r]);
            acc[r] = fmaf(a.w, w3, acc[r]);
        }
    }

    const float b = bias[c];
#pragma unroll
    for (int r = 0; r < ROWS; ++r) {
        float v = acc[r] + b;
        if (RELU) v = fmaxf(v, 0.0f);
        out[(size_t)(row0 + r) * NCOLS + c] = v;
    }
}

extern "C" void kernel_launch(void* const* d_in, const int* in_sizes, int n_in,
                              void* d_out, int out_size, void* d_ws, size_t ws_size,
                              hipStream_t stream) {
    const float* features = (const float*)d_in[0];
    const float* W1 = (const float*)d_in[1];
    const float* b1 = (const float*)d_in[2];
    const float* W2 = (const float*)d_in[3];
    const float* b2 = (const float*)d_in[4];
    const int* src0 = (const int*)d_in[5];
    const int* dst0 = (const int*)d_in[6];
    const int* src1 = (const int*)d_in[7];
    const int* dst1 = (const int*)d_in[8];
    const int E0 = in_sizes[5];
    const int E1 = in_sizes[7];
    const int NSRC0 = 100000, NDST0 = 20000, NDST1 = 4096;
    const int nA0 = (E0 + EPB - 1) / EPB;                      // 157
    const int nA1 = (E1 + EPB - 1) / EPB;                      // 32

    char* ws = (char*)d_ws;
    size_t off = 0;
    auto carve = [&](size_t bytes) -> void* {
        void* p = ws + off;
        off = (off + bytes + 255) & ~(size_t)255;
        return p;
    };
    // dense tables (bf16 path: fully written by finalize, NO memset needed;
    // fp32 fallback memsets [0, zero_span)). od buffers double as f32 norm
    // tables on the bf16 path (exclusive paths).
    int* od0  = (int*)carve((size_t)NSRC0 * 4);
    int* od1  = (int*)carve((size_t)NDST0 * 4);
    int* cnt0 = (int*)carve((size_t)NDST0 * 4);
    int* cnt1 = (int*)carve((size_t)NDST1 * 4);
    const size_t zero_span = off;
    int* esrc0p = (int*)carve((size_t)NDST0 * RSTRIDE * 4);
    int* esrc1p = (int*)carve((size_t)NDST1 * RSTRIDE * 4);
    uint4* pW1  = (uint4*)carve((size_t)8192 * 16);
    uint4* pW2  = (uint4*)carve((size_t)4096 * 16);
    int* cntD0 = (int*)carve((size_t)nA0 * G0_DB * 4);
    int* offD0 = (int*)carve((size_t)nA0 * G0_DB * 4);
    int* cntS0 = (int*)carve((size_t)nA0 * G0_SB * 4);
    int* offS0 = (int*)carve((size_t)nA0 * G0_SB * 4);
    int* cntD1 = (int*)carve((size_t)nA1 * G1_DB * 4);
    int* offD1 = (int*)carve((size_t)nA1 * G1_DB * 4);
    int* cntS1 = (int*)carve((size_t)nA1 * G1_SB * 4);
    int* offS1 = (int*)carve((size_t)nA1 * G1_SB * 4);
    unsigned* sortD0 = (unsigned*)carve((size_t)nA0 * EPB * 4);
    unsigned* sortS0 = (unsigned*)carve((size_t)nA0 * EPB * 4);
    unsigned* sortD1 = (unsigned*)carve((size_t)nA1 * EPB * 4);
    unsigned* sortS1 = (unsigned*)carve((size_t)nA1 * EPB * 4);
    unsigned short* xbufb = (unsigned short*)carve((size_t)NDST0 * K_DIM * 2);
    unsigned short* hfeat = (unsigned short*)carve((size_t)NSRC0 * K_DIM * 2);
    const size_t need_bf16 = off;
    (void)n_in; (void)out_size;

    if (ws_size >= need_bf16) {
        float* nv0 = (float*)od0;                              // f32 norm tables
        float* nv1 = (float*)od1;
        const int total_f = NSRC0 * K_DIM;
        const int castBlocks = (total_f / 8 + 255) / 256;      // 12500
        splitA_kernel<<<nA0 + nA1 + castBlocks + 48, 256, 0, stream>>>(
            src0, dst0, E0, src1, dst1, E1,
            cntD0, offD0, cntS0, offS0, sortD0, sortS0,
            cntD1, offD1, cntS1, offS1, sortD1, sortS1,
            nA0, nA1, features, hfeat, total_f, castBlocks,
            W1, pW1, W2, pW2);
        finalize_kernel<<<NB_FIN, 256, 0, stream>>>(
            nA0, nA1,
            sortD0, cntD0, offD0, cnt0, esrc0p,
            sortD1, cntD1, offD1, cnt1, esrc1p,
            sortS0, cntS0, offS0, nv0,
            sortS1, cntS1, offS1, nv1);
        fused0_kernel<<<NDST0 / 16, 512, 0, stream>>>(
            hfeat, esrc0p, cnt0, nv0, pW1, b1, nv1, xbufb);
        fused1_kernel<<<NDST1 / 16, 512, 0, stream>>>(
            xbufb, esrc1p, cnt1, pW2, b2, (float*)d_out);
    } else {
        // fp32 fallback: direct atomics on dense tables
        hipMemsetAsync(ws, 0, zero_span, stream);
        float* agg0 = (float*)carve((size_t)NDST0 * K_DIM * 4);
        float* xbuf = (float*)carve((size_t)NDST0 * K_DIM * 4);
        float* agg1 = (float*)carve((size_t)NDST1 * K_DIM * 4);
        edges_kernel<<<(E0 + E1 + 255) / 256, 256, 0, stream>>>(
            src0, dst0, od0, cnt0, esrc0p, E0,
            src1, dst1, od1, cnt1, esrc1p, E1);
        gatherf_kernel<<<(NDST0 + 3) / 4, 256, 0, stream>>>(features, esrc0p, cnt0, od0,
                                                            agg0, NDST0);
        gemm_kernel<16, 256, true><<<NDST0 / 16, 256, 0, stream>>>(agg0, W1, b1, xbuf, NDST0);
        gatherf_kernel<<<(NDST1 + 3) / 4, 256, 0, stream>>>(xbuf, esrc1p, cnt1, od1,
                                                            agg1, NDST1);
        gemm_kernel<4, 128, false><<<NDST1 / 4, 128, 0, stream>>>(agg1, W2, b2,
                                                                  (float*)d_out, NDST1);
    }
}